// Round 2
// baseline (407.592 us; speedup 1.0000x reference)
//
#include <hip/hip_runtime.h>

#define N_   32
#define C_   512
#define H_   56
#define W_   56
#define S_   16    // NUM_SPLIT
#define CP_  32    // channels per split
#define HW_  (H_*W_)              // 3136
#define TOT_ ((size_t)N_*C_*HW_)  // 51380224

__constant__ int d_mx[16] = {0,0,6,0,0,1,1,4,5,1,3,0,0,0,3,2};
__constant__ int d_my[16] = {0,1,0,5,2,0,2,0,0,6,0,4,6,3,5,2};

// ---------------- Kernel 1: adaptive avg pool 56x56 -> 7x7 -------------------
// One 64-thread wave per (n,c) plane; lanes 0..48 each own one 8x8 block.
__global__ void __launch_bounds__(64) pool_kernel(const float* __restrict__ x,
                                                  float* __restrict__ xp) {
    int plane = blockIdx.x;            // n*C_ + c
    int t = threadIdx.x;
    if (t >= 49) return;
    int oi = t / 7, oj = t % 7;
    const float* p = x + (size_t)plane * HW_ + (oi * 8) * W_ + oj * 8;
    float sum = 0.f;
#pragma unroll
    for (int r = 0; r < 8; ++r) {
        float4 a = *reinterpret_cast<const float4*>(p + r * W_);
        float4 b = *reinterpret_cast<const float4*>(p + r * W_ + 4);
        sum += a.x + a.y + a.z + a.w + b.x + b.y + b.z + b.w;
    }
    xp[(size_t)plane * 49 + t] = sum * (1.0f / 64.0f);
}

// ---------------- Kernel 2: head (convs + DCT blend + MLP) -> cw -------------
// One 256-thread block per sample. Work is tiny (latency-bound).
__global__ void __launch_bounds__(256) head_kernel(
        const float* __restrict__ xp,
        const float* __restrict__ c1w, const float* __restrict__ c1b,
        const float* __restrict__ c2w, const float* __restrict__ c2b,
        const float* __restrict__ w1,  const float* __restrict__ w2,
        float* __restrict__ cwout) {
    __shared__ float sD[7][7];
    __shared__ float a1[S_ * 9];
    __shared__ float wcomb[S_ * 49];
    __shared__ float svec[C_];
    __shared__ float hmid[32];
    __shared__ float sfrac[S_];
    __shared__ int   sleft[S_];

    int n = blockIdx.x, t = threadIdx.x;
    const float* xpn = xp + (size_t)n * C_ * 49;

    // DCT table: D[f][p] = cos(pi*f*(p+0.5)/7)/sqrt(7), rows f>=1 * sqrt(2)
    if (t < 49) {
        int f = t / 7, p = t % 7;
        float v = cosf(3.14159265358979323846f * f * (p + 0.5f) / 7.0f) * 0.3779644730092272f;
        if (f >= 1) v *= 1.4142135623730951f;
        sD[f][p] = v;
    }
    __syncthreads();

    // conv1: grouped 3x3, stride 2, VALID on 7x7 -> 3x3 per split; hard_sigmoid
    if (t < S_ * 9) {
        int s = t / 9, o = t - s * 9, oi = o / 3, oj = o - oi * 3;
        float acc = c1b[s];
        const float* xb = xpn + s * CP_ * 49;
        const float* wb = c1w + s * CP_ * 9;
        for (int ic = 0; ic < CP_; ++ic) {
#pragma unroll
            for (int ki = 0; ki < 3; ++ki)
#pragma unroll
                for (int kj = 0; kj < 3; ++kj)
                    acc += xb[ic * 49 + (oi * 2 + ki) * 7 + (oj * 2 + kj)]
                         * wb[ic * 9 + ki * 3 + kj];
        }
        a1[t] = fminf(fmaxf(acc + 3.f, 0.f), 6.f) * (1.f / 6.f);  // hard_sigmoid
    }
    __syncthreads();

    // conv2: depthwise 3x3 stride 2 VALID on 3x3 -> 1; pred = clip(v*16, 0, 14.9)
    if (t < S_) {
        float acc = c2b[t];
#pragma unroll
        for (int k = 0; k < 9; ++k) acc += a1[t * 9 + k] * c2w[t * 9 + k];
        float pred = fminf(fmaxf(acc * 16.f, 0.f), 14.9f);
        int l = (int)pred;
        sleft[t] = l;
        sfrac[t] = pred - (float)l;
    }
    __syncthreads();

    // Combined DCT filter per split: (1-frac)*W_left + frac*W_right (linear fold)
    for (int i = t; i < S_ * 49; i += 256) {
        int s = i / 49, p = i - s * 49, hh = p / 7, ww = p - hh * 7;
        int l = sleft[s], r = l + 1;
        float fr = sfrac[s];
        wcomb[i] = (1.f - fr) * sD[d_mx[l]][hh] * sD[d_my[l]][ww]
                 +        fr  * sD[d_mx[r]][hh] * sD[d_my[r]][ww];
    }
    __syncthreads();

    // res: per-channel 49-dot with its split's filter -> svec[512]
    for (int ch = t; ch < C_; ch += 256) {
        const float* xb = xpn + ch * 49;
        const float* wb = &wcomb[(ch >> 5) * 49];
        float acc = 0.f;
#pragma unroll
        for (int p = 0; p < 49; ++p) acc += xb[p] * wb[p];
        svec[ch] = acc;
    }
    __syncthreads();

    // hmid = hard_sigmoid(svec @ w1.T), w1 is (32,512) row-major
    if (t < 32) {
        float acc = 0.f;
        const float* wr = w1 + t * C_;
        for (int k = 0; k < C_; ++k) acc += svec[k] * wr[k];
        hmid[t] = fminf(fmaxf(acc + 3.f, 0.f), 6.f) * (1.f / 6.f);
    }
    __syncthreads();

    // cw = sigmoid(hmid @ w2.T), w2 is (512,32) row-major
    for (int ch = t; ch < C_; ch += 256) {
        float acc = 0.f;
        const float* wr = w2 + ch * 32;
#pragma unroll
        for (int j = 0; j < 32; ++j) acc += hmid[j] * wr[j];
        cwout[n * C_ + ch] = 1.f / (1.f + expf(-acc));
    }
}

// ---------------- Kernel 3: out = x * cw[n,c] --------------------------------
// float4 per thread; 3136 % 4 == 0 so each vec4 stays within one plane.
__global__ void __launch_bounds__(256) scale_kernel(const float* __restrict__ x,
                                                    const float* __restrict__ cw,
                                                    float* __restrict__ out) {
    unsigned int i = blockIdx.x * 256u + threadIdx.x;   // vec4 index
    unsigned int plane = i / 784u;                       // 3136/4 vec4 per plane
    float wsc = cw[plane];
    float4 u = reinterpret_cast<const float4*>(x)[i];
    u.x *= wsc; u.y *= wsc; u.z *= wsc; u.w *= wsc;
    reinterpret_cast<float4*>(out)[i] = u;
}

extern "C" void kernel_launch(void* const* d_in, const int* in_sizes, int n_in,
                              void* d_out, int out_size, void* d_ws, size_t ws_size,
                              hipStream_t stream) {
    const float* x   = (const float*)d_in[0];
    const float* c1w = (const float*)d_in[1];
    const float* c1b = (const float*)d_in[2];
    const float* c2w = (const float*)d_in[3];
    const float* c2b = (const float*)d_in[4];
    const float* w1  = (const float*)d_in[5];
    const float* w2  = (const float*)d_in[6];
    float* out = (float*)d_out;

    float* xp    = (float*)d_ws;                 // N*C*49 fp32 = 3.2 MB
    float* cwbuf = xp + (size_t)N_ * C_ * 49;    // N*C fp32

    pool_kernel<<<N_ * C_, 64, 0, stream>>>(x, xp);
    head_kernel<<<N_, 256, 0, stream>>>(xp, c1w, c1b, c2w, c2b, w1, w2, cwbuf);
    scale_kernel<<<(unsigned)(TOT_ / 4 / 256), 256, 0, stream>>>(x, cwbuf, out);
}

// Round 3
// 401.626 us; speedup vs baseline: 1.0149x; 1.0149x over previous
//
#include <hip/hip_runtime.h>

#define N_   32
#define C_   512
#define H_   56
#define W_   56
#define S_   16    // NUM_SPLIT
#define CP_  32    // channels per split
#define HW_  (H_*W_)              // 3136
#define TOT_ ((size_t)N_*C_*HW_)  // 51380224

__constant__ int d_mx[16] = {0,0,6,0,0,1,1,4,5,1,3,0,0,0,3,2};
__constant__ int d_my[16] = {0,1,0,5,2,0,2,0,0,6,0,4,6,3,5,2};

// ---------------- Kernel 1: adaptive avg pool 56x56 -> 7x7 -------------------
// One plane per 256-thread block. Fully-coalesced float4 global reads staged
// through LDS, then 8x8 block sums from LDS (196 threads, quarter-block each).
__global__ void __launch_bounds__(256) pool_kernel(const float* __restrict__ x,
                                                   float* __restrict__ xp) {
    __shared__ float tile[HW_];       // 12.5 KB
    __shared__ float part[49 * 4];
    int plane = blockIdx.x;           // n*C_ + c
    int t = threadIdx.x;
    const float4* src = reinterpret_cast<const float4*>(x + (size_t)plane * HW_);
    for (int i = t; i < HW_ / 4; i += 256)            // 784 float4, coalesced
        *reinterpret_cast<float4*>(&tile[i * 4]) = src[i];
    __syncthreads();
    if (t < 196) {
        int bin = t >> 2, q = t & 3;                  // quarter-block = 2 rows x 8 cols
        int oi = bin / 7, oj = bin % 7;
        const float* rp = &tile[(oi * 8 + q * 2) * W_ + oj * 8];
        float s = 0.f;
#pragma unroll
        for (int rr = 0; rr < 2; ++rr)
#pragma unroll
            for (int cc = 0; cc < 8; ++cc) s += rp[rr * W_ + cc];
        part[t] = s;
    }
    __syncthreads();
    if (t < 49) {
        float s = part[t * 4] + part[t * 4 + 1] + part[t * 4 + 2] + part[t * 4 + 3];
        xp[(size_t)plane * 49 + t] = s * (1.0f / 64.0f);
    }
}

// ---------------- Kernel 2: head (convs + DCT blend + MLP) -> cw -------------
// One 256-thread block per sample. xp staged into LDS in two 50 KB chunks
// (8 splits each) with coalesced float4 loads; all phases LDS/register-fed.
__global__ void __launch_bounds__(256) head_kernel(
        const float* __restrict__ xp,
        const float* __restrict__ c1w, const float* __restrict__ c1b,
        const float* __restrict__ c2w, const float* __restrict__ c2b,
        const float* __restrict__ w1,  const float* __restrict__ w2,
        float* __restrict__ cwout) {
    __shared__ float tile[8 * CP_ * 49];   // 12544 floats = 50 KB (one chunk)
    __shared__ float sD[7][7];
    __shared__ float a1[S_ * 9];
    __shared__ float wcomb[S_ * 49];
    __shared__ float svec[C_];
    __shared__ float hpart[256];
    __shared__ float hmid[32];
    __shared__ float sfrac[S_];
    __shared__ int   sleft[S_];

    int n = blockIdx.x, t = threadIdx.x;
    const float* xpn = xp + (size_t)n * C_ * 49;

    if (t < 49) {
        int f = t / 7, p = t % 7;
        float v = cosf(3.14159265358979323846f * f * (p + 0.5f) / 7.0f) * 0.3779644730092272f;
        if (f >= 1) v *= 1.4142135623730951f;
        sD[f][p] = v;
    }

    // -------- conv1 over two LDS chunks (8 splits = 12544 floats each) -------
    for (int chunk = 0; chunk < 2; ++chunk) {
        __syncthreads();               // protect tile from previous phase
        const float4* src = reinterpret_cast<const float4*>(xpn + chunk * 8 * CP_ * 49);
        for (int i = t; i < 8 * CP_ * 49 / 4; i += 256)
            *reinterpret_cast<float4*>(&tile[i * 4]) = src[i];
        __syncthreads();
        if (t < 72) {                  // 8 splits x 9 outputs
            int sl = t / 9, o = t - sl * 9, oi = o / 3, oj = o - oi * 3;
            int s = chunk * 8 + sl;
            float acc = c1b[s];
            const float* xb = &tile[sl * CP_ * 49];
            const float* wb = c1w + s * CP_ * 9;
            for (int ic = 0; ic < CP_; ++ic) {
#pragma unroll
                for (int ki = 0; ki < 3; ++ki)
#pragma unroll
                    for (int kj = 0; kj < 3; ++kj)
                        acc += xb[ic * 49 + (oi * 2 + ki) * 7 + (oj * 2 + kj)]
                             * wb[ic * 9 + ki * 3 + kj];
            }
            a1[s * 9 + o] = fminf(fmaxf(acc + 3.f, 0.f), 6.f) * (1.f / 6.f);
        }
    }
    __syncthreads();
    // NOTE: tile still holds splits 8..15 (channels 256..511) — reused below.

    // -------- conv2 (depthwise 3x3 on 3x3 -> 1), pred ------------------------
    if (t < S_) {
        float acc = c2b[t];
#pragma unroll
        for (int k = 0; k < 9; ++k) acc += a1[t * 9 + k] * c2w[t * 9 + k];
        float pred = fminf(fmaxf(acc * 16.f, 0.f), 14.9f);
        int l = (int)pred;
        sleft[t] = l;
        sfrac[t] = pred - (float)l;
    }
    __syncthreads();

    // -------- combined DCT filter per split ----------------------------------
    for (int i = t; i < S_ * 49; i += 256) {
        int s = i / 49, p = i - s * 49, hh = p / 7, ww = p - hh * 7;
        int l = sleft[s], r = l + 1;
        float fr = sfrac[s];
        wcomb[i] = (1.f - fr) * sD[d_mx[l]][hh] * sD[d_my[l]][ww]
                 +        fr  * sD[d_mx[r]][hh] * sD[d_my[r]][ww];
    }
    __syncthreads();

    // -------- svec: per-channel 49-dot ---------------------------------------
    for (int ch = t; ch < C_; ch += 256) {
        const float* xb = (ch < 256) ? (xpn + ch * 49)          // global (L2-hot)
                                     : (&tile[(ch - 256) * 49]); // LDS chunk 2
        const float* wb = &wcomb[(ch >> 5) * 49];
        float acc = 0.f;
#pragma unroll
        for (int p = 0; p < 49; ++p) acc += xb[p] * wb[p];
        svec[ch] = acc;
    }
    __syncthreads();

    // -------- hmid = hard_sigmoid(svec @ w1.T), parallel over 256 threads ----
    {
        int o = t >> 3, g = t & 7;     // 32 outputs x 8 chunks of 64
        const float4* wv = reinterpret_cast<const float4*>(w1 + o * C_ + g * 64);
        const float4* sv = reinterpret_cast<const float4*>(&svec[g * 64]);
        float acc = 0.f;
#pragma unroll
        for (int j = 0; j < 16; ++j) {
            float4 a = sv[j], b = wv[j];
            acc += a.x * b.x + a.y * b.y + a.z * b.z + a.w * b.w;
        }
        hpart[t] = acc;
    }
    __syncthreads();
    if (t < 32) {
        float acc = 0.f;
#pragma unroll
        for (int g = 0; g < 8; ++g) acc += hpart[t * 8 + g];
        hmid[t] = fminf(fmaxf(acc + 3.f, 0.f), 6.f) * (1.f / 6.f);
    }
    __syncthreads();

    // -------- cw = sigmoid(hmid @ w2.T) --------------------------------------
    for (int ch = t; ch < C_; ch += 256) {
        const float4* wr = reinterpret_cast<const float4*>(w2 + ch * 32);
        float acc = 0.f;
#pragma unroll
        for (int j = 0; j < 8; ++j) {
            float4 b = wr[j];
            const float4 h = reinterpret_cast<const float4*>(hmid)[j];
            acc += h.x * b.x + h.y * b.y + h.z * b.z + h.w * b.w;
        }
        cwout[n * C_ + ch] = 1.f / (1.f + expf(-acc));
    }
}

// ---------------- Kernel 3: out = x * cw[n,c] --------------------------------
__global__ void __launch_bounds__(256) scale_kernel(const float* __restrict__ x,
                                                    const float* __restrict__ cw,
                                                    float* __restrict__ out) {
    unsigned int i = blockIdx.x * 256u + threadIdx.x;   // vec4 index
    unsigned int plane = i / 784u;                       // 3136/4 vec4 per plane
    float wsc = cw[plane];
    float4 u = reinterpret_cast<const float4*>(x)[i];
    u.x *= wsc; u.y *= wsc; u.z *= wsc; u.w *= wsc;
    reinterpret_cast<float4*>(out)[i] = u;
}

extern "C" void kernel_launch(void* const* d_in, const int* in_sizes, int n_in,
                              void* d_out, int out_size, void* d_ws, size_t ws_size,
                              hipStream_t stream) {
    const float* x   = (const float*)d_in[0];
    const float* c1w = (const float*)d_in[1];
    const float* c1b = (const float*)d_in[2];
    const float* c2w = (const float*)d_in[3];
    const float* c2b = (const float*)d_in[4];
    const float* w1  = (const float*)d_in[5];
    const float* w2  = (const float*)d_in[6];
    float* out = (float*)d_out;

    float* xp    = (float*)d_ws;                 // N*C*49 fp32 = 3.2 MB
    float* cwbuf = xp + (size_t)N_ * C_ * 49;    // N*C fp32

    pool_kernel<<<N_ * C_, 256, 0, stream>>>(x, xp);
    head_kernel<<<N_, 256, 0, stream>>>(xp, c1w, c1b, c2w, c2b, w1, w2, cwbuf);
    scale_kernel<<<(unsigned)(TOT_ / 4 / 256), 256, 0, stream>>>(x, cwbuf, out);
}